// Round 1
// 1112.193 us; speedup vs baseline: 1.1243x; 1.1243x over previous
//
#include <hip/hip_runtime.h>

typedef _Float16 half_t;
typedef _Float16 half4_t __attribute__((ext_vector_type(4)));
typedef _Float16 half8_t __attribute__((ext_vector_type(8)));
typedef float float4_t __attribute__((ext_vector_type(4)));

#define S_LEN 4096
#define NB 4
#define H_DIM 1024

#define MFMA16(a, b, c) __builtin_amdgcn_mfma_f32_16x16x32_f16(a, b, c, 0, 0, 0)

// ---------------------------------------------------------------------------
// Kernel 0: transpose + fp16-split W -> Wt_hi/Wt_lo [h][f] (scratch in d_out;
// flash_attn overwrites all of d_out afterwards).
// ---------------------------------------------------------------------------
__global__ __launch_bounds__(256) void wt_prep(
    const float* __restrict__ Wq, const float* __restrict__ Wk,
    const float* __restrict__ Wv, half_t* __restrict__ wth,
    half_t* __restrict__ wtl) {
  const int zi = blockIdx.z;
  const float* W = (zi == 0) ? Wq : (zi == 1) ? Wk : Wv;
  half_t* oh = wth + (size_t)zi * H_DIM * H_DIM;
  half_t* ol = wtl + (size_t)zi * H_DIM * H_DIM;
  const int h0 = blockIdx.x * 32, f0 = blockIdx.y * 32;
  __shared__ float Ws[32][33];
  const int t = threadIdx.x;
  const int c = t & 31, r8 = t >> 5;
#pragma unroll
  for (int rr = 0; rr < 4; rr++)
    Ws[r8 * 4 + rr][c] = W[(size_t)(f0 + r8 * 4 + rr) * H_DIM + h0 + c];
  __syncthreads();
#pragma unroll
  for (int rr = 0; rr < 4; rr++) {
    int h = r8 * 4 + rr;
    float v = Ws[c][h];
    half_t hi = (half_t)v;
    half_t lo = (half_t)(v - (float)hi);
    oh[(size_t)(h0 + h) * H_DIM + f0 + c] = hi;
    ol[(size_t)(h0 + h) * H_DIM + f0 + c] = lo;
  }
}

// ---------------------------------------------------------------------------
// Kernel 1: QKV projection on MFMA, 3-term fp16 split (hh + lh + hl).
// (unchanged)
// ---------------------------------------------------------------------------
#define QKV_BK 64

__global__ __launch_bounds__(256, 2) void qkv_mfma(
    const float* __restrict__ x, const half_t* __restrict__ wth,
    const half_t* __restrict__ wtl, const float* __restrict__ bq,
    const float* __restrict__ bk, const float* __restrict__ bv,
    half_t* __restrict__ ws) {
  const int zi = blockIdx.z;
  const half_t* Ah_g = wth + (size_t)zi * H_DIM * H_DIM;
  const half_t* Al_g = wtl + (size_t)zi * H_DIM * H_DIM;
  const float* bias = (zi == 0) ? bq : (zi == 1) ? bk : bv;
  half_t* out = ws + (size_t)zi * ((size_t)NB * S_LEN * H_DIM);
  const int m0 = blockIdx.x * 128;  // h
  const int n0 = blockIdx.y * 128;  // flattened b*s
  const int t = threadIdx.x;
  const int w = t >> 6, lane = t & 63, ln = lane & 15, quad = lane >> 4;

  __shared__ half_t Bs[16384];

  float4_t acc[2][8] = {};

  const int ss = t >> 1;
  const int fh = (t & 1) * 32;
  const int snt = ss >> 4, sln = ss & 15;

  for (int k0 = 0; k0 < H_DIM; k0 += QKV_BK) {
    half8_t ah[2][2], al[2][2];
#pragma unroll
    for (int i = 0; i < 2; i++) {
      const size_t arow =
          (size_t)(m0 + w * 32 + i * 16 + ln) * H_DIM + k0 + quad * 8;
#pragma unroll
      for (int k2 = 0; k2 < 2; k2++) {
        ah[i][k2] = *(const half8_t*)(Ah_g + arow + k2 * 32);
        al[i][k2] = *(const half8_t*)(Al_g + arow + k2 * 32);
      }
    }
    __syncthreads();
    {
      const float* xp = x + (size_t)(n0 + ss) * H_DIM + k0 + fh;
#pragma unroll
      for (int g = 0; g < 4; g++) {
        float4 v0 = *(const float4*)(xp + g * 8);
        float4 v1 = *(const float4*)(xp + g * 8 + 4);
        float vv[8] = {v0.x, v0.y, v0.z, v0.w, v1.x, v1.y, v1.z, v1.w};
        half8_t hhi, hlo;
#pragma unroll
        for (int j = 0; j < 8; j++) {
          half_t h = (half_t)vv[j];
          hhi[j] = h;
          hlo[j] = (half_t)(vv[j] - (float)h);
        }
        int f = fh + g * 8;
        int k2 = f >> 5, qd = (f >> 3) & 3;
        int base = ((k2 * 8 + snt) * 64 + qd * 16 + sln) * 8;
        *(half8_t*)&Bs[base] = hhi;
        *(half8_t*)&Bs[8192 + base] = hlo;
      }
    }
    __syncthreads();
#pragma unroll
    for (int k2 = 0; k2 < 2; k2++) {
#pragma unroll
      for (int nt = 0; nt < 8; nt++) {
        int base = ((k2 * 8 + nt) * 64 + lane) * 8;
        half8_t bh = *(const half8_t*)&Bs[base];
        half8_t bl = *(const half8_t*)&Bs[8192 + base];
        acc[0][nt] = MFMA16(ah[0][k2], bh, acc[0][nt]);
        acc[1][nt] = MFMA16(ah[1][k2], bh, acc[1][nt]);
        acc[0][nt] = MFMA16(al[0][k2], bh, acc[0][nt]);
        acc[1][nt] = MFMA16(al[1][k2], bh, acc[1][nt]);
        acc[0][nt] = MFMA16(ah[0][k2], bl, acc[0][nt]);
        acc[1][nt] = MFMA16(ah[1][k2], bl, acc[1][nt]);
      }
    }
  }

  const float oscale = (zi == 0) ? 0.03125f : 1.0f;
  float bb[2][4];
#pragma unroll
  for (int i = 0; i < 2; i++)
#pragma unroll
    for (int r = 0; r < 4; r++)
      bb[i][r] = bias[m0 + w * 32 + i * 16 + quad * 4 + r];

  if (zi < 2) {
#pragma unroll
    for (int i = 0; i < 2; i++)
#pragma unroll
      for (int nt = 0; nt < 8; nt++) {
        half4_t h4;
#pragma unroll
        for (int r = 0; r < 4; r++)
          h4[r] = (half_t)((acc[i][nt][r] + bb[i][r]) * oscale);
        size_t s = n0 + nt * 16 + ln;
        *(half4_t*)&out[s * H_DIM + m0 + w * 32 + i * 16 + quad * 4] = h4;
      }
  } else {
#pragma unroll
    for (int i = 0; i < 2; i++)
#pragma unroll
      for (int nt = 0; nt < 8; nt++) {
        int sf = n0 + nt * 16 + ln;
        int b = sf >> 12, si = sf & 4095;
#pragma unroll
        for (int r = 0; r < 4; r++) {
          int h = m0 + w * 32 + i * 16 + quad * 4 + r;
          out[((size_t)b * H_DIM + h) * S_LEN + si] =
              (half_t)(acc[i][nt][r] + bb[i][r]);
        }
      }
  }
}

// ---------------------------------------------------------------------------
// Kernel 2: MFMA flash attention, TQ=64 (512 threads, 8 waves, 1 block/CU).
// Phase A restructured vs previous round: each wave owns a DISJOINT 16-row
// K chunk (16 S-cols) and computes all 64 Q rows against it -> the K tile is
// read from cache exactly ONCE per block-iter (was twice: qh=0/qh=1 wave
// groups duplicated the K stream). Cache traffic/iter: 768 KB -> 512 KB.
// PV phase unchanged: wave = h-128-chunk, V disjoint, P broadcast from LDS.
// LDS: Qs 128 KB + Ps 16 KB + reduce bufs ~5 KB.
// ---------------------------------------------------------------------------
#define TQ 64
#define TK 128

__global__ __launch_bounds__(512, 2) void flash_attn(
    const half_t* __restrict__ qw, const half_t* __restrict__ kw,
    const half_t* __restrict__ vt, float* __restrict__ out) {
  // batch -> 2 XCDs; 32 blocks/XCD share one K/V stream, 1 block/CU.
  const int slot = blockIdx.x & 7;
  const int b = slot >> 1;
  const int qb = ((blockIdx.x >> 3) << 1) | (slot & 1);
  const int q0 = qb * TQ;
  const int t = threadIdx.x;
  const int w = t >> 6;
  const int lane = t & 63;
  const int ln = lane & 15;
  const int quad = lane >> 4;

  __shared__ half_t Qs[65536];  // [rs(4)][ks(32)][lane(64)][8] = 128 KB
  __shared__ half_t Ps[8192];   // [rs(4)][kc(4)][lane(64)][8] = 16 KB
  __shared__ float wmax[8][64];
  __shared__ float wl[8][64];
  __shared__ float mS[64], lS[64], aS[64];

  const half_t* qp = qw + ((size_t)b * S_LEN + q0) * H_DIM;
  const half_t* kbp = kw + (size_t)b * S_LEN * H_DIM;
  const half_t* vbt = vt + (size_t)b * H_DIM * S_LEN;

  // stage Q tile into fragment order
#pragma unroll
  for (int i = 0; i < 16; i++) {
    int flat = t * 8 + i * 4096;
    int r = flat >> 10, c = flat & 1023;
    int rs = r >> 4, lq = r & 15, ks = c >> 5, qd = (c >> 3) & 3;
    *(half8_t*)&Qs[((rs * 32 + ks) * 64 + qd * 16 + lq) * 8] =
        *(const half8_t*)&qp[(size_t)r * H_DIM + c];
  }
  if (t < 64) {
    mS[t] = -1e30f;
    lS[t] = 0.0f;
  }
  __syncthreads();

  float4_t O[4][8] = {};  // [rs(4 row-tiles)][j(8 col-tiles in h-chunk w)]

  for (int kt = 0; kt < S_LEN; kt += TK) {
    // ---------------- phase A: S = Q . K^T ----------------
    // wave w: K rows kt + w*16 .. +16 (S-cols w*16..+16 of the 128 tile),
    // all 4 Q row-sets. K tile read once per block.
    float4_t s[4] = {};
    const half_t* kr = kbp + (size_t)(kt + w * 16 + ln) * H_DIM + quad * 8;
    half8_t kbuf[6];
#pragma unroll
    for (int d = 0; d < 6; d++) kbuf[d] = *(const half8_t*)(kr + d * 32);
#pragma unroll
    for (int ks = 0; ks < 32; ks++) {
      half8_t a0 = *(const half8_t*)&Qs[(ks * 64 + lane) * 8];
      half8_t a1 = *(const half8_t*)&Qs[16384 + (ks * 64 + lane) * 8];
      half8_t a2 = *(const half8_t*)&Qs[32768 + (ks * 64 + lane) * 8];
      half8_t a3 = *(const half8_t*)&Qs[49152 + (ks * 64 + lane) * 8];
      half8_t kc = kbuf[ks % 6];
      if (ks < 26) kbuf[ks % 6] = *(const half8_t*)(kr + (ks + 6) * 32);
      s[0] = MFMA16(a0, kc, s[0]);
      s[1] = MFMA16(a1, kc, s[1]);
      s[2] = MFMA16(a2, kc, s[2]);
      s[3] = MFMA16(a3, kc, s[3]);
    }

    // early V prefetch (u=0,1) — hides L2 latency under softmax
    const half_t* vbase = vbt + (size_t)(w * 128 + ln) * S_LEN + kt + quad * 8;
    half8_t vbuf[3][2];
#pragma unroll
    for (int u = 0; u < 2; u++)
#pragma unroll
      for (int c = 0; c < 2; c++)
        vbuf[u][c] =
            *(const half8_t*)(vbase + (size_t)u * 16 * S_LEN + c * 32);

    // ---------------- softmax stats ----------------
    // s[rs][r]: row q = rs*16 + quad*4 + r, col = w*16 + ln.
    float rm[4][4];
#pragma unroll
    for (int rs = 0; rs < 4; rs++)
#pragma unroll
      for (int r = 0; r < 4; r++) rm[rs][r] = s[rs][r];
#pragma unroll
    for (int off = 1; off < 16; off <<= 1)
#pragma unroll
      for (int rs = 0; rs < 4; rs++)
#pragma unroll
        for (int r = 0; r < 4; r++)
          rm[rs][r] = fmaxf(rm[rs][r], __shfl_xor(rm[rs][r], off));
    if (ln == 0)
#pragma unroll
      for (int rs = 0; rs < 4; rs++)
#pragma unroll
        for (int r = 0; r < 4; r++)
          wmax[w][rs * 16 + quad * 4 + r] = rm[rs][r];
    __syncthreads();  // W1
    if (t < 64) {
      float nm = mS[t];
#pragma unroll
      for (int w2 = 0; w2 < 8; w2++) nm = fmaxf(nm, wmax[w2][t]);
      aS[t] = __expf(mS[t] - nm);
      mS[t] = nm;
    }
    __syncthreads();  // W2

    // ---------------- P = exp(S - m) -> Ps (fragment order) ---------------
    float nmv[4][4];
#pragma unroll
    for (int rs = 0; rs < 4; rs++)
#pragma unroll
      for (int r = 0; r < 4; r++) nmv[rs][r] = mS[rs * 16 + quad * 4 + r];
    // Ps addr for P[q][k'] (k' = w*16+ln in 128-tile): tile (rs*4 + (w>>1)),
    // lane_c = (q&15) | ((k32>>3)<<4) with k32 = (w&1)*16+ln, j = ln&7.
    const int pbase = (w >> 1) * 512 + (w & 1) * 256 + (ln >> 3) * 128 +
                      quad * 32 + (ln & 7);
    float pl[4][4];
#pragma unroll
    for (int rs = 0; rs < 4; rs++)
#pragma unroll
      for (int r = 0; r < 4; r++) {
        float p = __expf(s[rs][r] - nmv[rs][r]);
        pl[rs][r] = p;
        Ps[pbase + rs * 2048 + r * 8] = (half_t)p;
      }
#pragma unroll
    for (int off = 1; off < 16; off <<= 1)
#pragma unroll
      for (int rs = 0; rs < 4; rs++)
#pragma unroll
        for (int r = 0; r < 4; r++) pl[rs][r] += __shfl_xor(pl[rs][r], off);
    if (ln == 0)
#pragma unroll
      for (int rs = 0; rs < 4; rs++)
#pragma unroll
        for (int r = 0; r < 4; r++)
          wl[w][rs * 16 + quad * 4 + r] = pl[rs][r];
    __syncthreads();  // W3
    if (t < 64) {
      float s8 = 0.f;
#pragma unroll
      for (int w2 = 0; w2 < 8; w2++) s8 += wl[w2][t];
      lS[t] = lS[t] * aS[t] + s8;
    }

    // ---------------- rescale O by alpha ----------------
    float al[4][4];
#pragma unroll
    for (int rs = 0; rs < 4; rs++)
#pragma unroll
      for (int r = 0; r < 4; r++) al[rs][r] = aS[rs * 16 + quad * 4 + r];
#pragma unroll
    for (int rs = 0; rs < 4; rs++)
#pragma unroll
      for (int j = 0; j < 8; j++)
#pragma unroll
        for (int r = 0; r < 4; r++) O[rs][j][r] *= al[rs][r];

    // ---------------- phase C: O += P @ V ----------------
    half8_t pa[4][2];
#pragma unroll
    for (int u = 0; u < 16; u++) {
      const int kc2 = u >> 3, j = u & 7;
      if ((u & 7) == 0) {
#pragma unroll
        for (int rs = 0; rs < 4; rs++)
#pragma unroll
          for (int c = 0; c < 2; c++)
            pa[rs][c] =
                *(const half8_t*)&Ps[((rs * 4 + kc2 * 2 + c) * 64 + lane) * 8];
      }
      if (u < 14) {
        const int un = u + 2;
#pragma unroll
        for (int c = 0; c < 2; c++)
          vbuf[un % 3][c] = *(const half8_t*)(
              vbase + (size_t)(un & 7) * 16 * S_LEN +
              ((un >> 3) * 2 + c) * 32);
      }
#pragma unroll
      for (int c = 0; c < 2; c++)
#pragma unroll
        for (int rs = 0; rs < 4; rs++)
          O[rs][j] = MFMA16(pa[rs][c], vbuf[u % 3][c], O[rs][j]);
    }
  }

  // ---------------- epilogue ----------------
  __syncthreads();
  float il[4][4];
#pragma unroll
  for (int rs = 0; rs < 4; rs++)
#pragma unroll
    for (int r = 0; r < 4; r++) il[rs][r] = 1.0f / lS[rs * 16 + quad * 4 + r];
  float* ob = out + ((size_t)b * S_LEN + q0) * H_DIM + w * 128 + ln;
#pragma unroll
  for (int rs = 0; rs < 4; rs++)
#pragma unroll
    for (int j = 0; j < 8; j++)
#pragma unroll
      for (int r = 0; r < 4; r++)
        ob[(size_t)(rs * 16 + quad * 4 + r) * H_DIM + j * 16] =
            O[rs][j][r] * il[rs][r];
}

// ---------------------------------------------------------------------------
extern "C" void kernel_launch(void* const* d_in, const int* in_sizes, int n_in,
                              void* d_out, int out_size, void* d_ws,
                              size_t ws_size, hipStream_t stream) {
  const float* x = (const float*)d_in[0];
  const float* Wq = (const float*)d_in[1];
  const float* bq = (const float*)d_in[2];
  const float* Wk = (const float*)d_in[3];
  const float* bk = (const float*)d_in[4];
  const float* Wv = (const float*)d_in[5];
  const float* bv = (const float*)d_in[6];
  half_t* ws = (half_t*)d_ws;  // q(32MB) | k(32MB) | vt(32MB, transposed)
  float* out = (float*)d_out;

  half_t* wth = (half_t*)d_out;  // scratch; overwritten by flash_attn
  half_t* wtl = wth + (size_t)3 * H_DIM * H_DIM;

  wt_prep<<<dim3(32, 32, 3), 256, 0, stream>>>(Wq, Wk, Wv, wth, wtl);

  qkv_mfma<<<dim3(8, 128, 3), 256, 0, stream>>>(x, wth, wtl, bq, bk, bv, ws);

  const half_t* qw = ws;
  const half_t* kw = ws + (size_t)NB * S_LEN * H_DIM;
  const half_t* vt = ws + 2 * (size_t)NB * S_LEN * H_DIM;
  flash_attn<<<dim3((S_LEN / TQ) * NB), 512, 0, stream>>>(qw, kw, vt, out);
}

// Round 3
// 1075.251 us; speedup vs baseline: 1.1629x; 1.0344x over previous
//
#include <hip/hip_runtime.h>

typedef _Float16 half_t;
typedef _Float16 half4_t __attribute__((ext_vector_type(4)));
typedef _Float16 half8_t __attribute__((ext_vector_type(8)));
typedef float float4_t __attribute__((ext_vector_type(4)));

#define S_LEN 4096
#define NB 4
#define H_DIM 1024

#define MFMA16(a, b, c) __builtin_amdgcn_mfma_f32_16x16x32_f16(a, b, c, 0, 0, 0)

// LDS-only barrier, guide-verified pattern (m201 8-phase template):
// wait local (LDS) ops only, then the compiler-visible barrier builtin.
// Global loads stay in flight across it (no vmcnt(0) drain). All cross-wave
// communication in flash_attn is via LDS; global loads are wave-private.
#define BAR_LDS()                                      \
  do {                                                 \
    asm volatile("s_waitcnt lgkmcnt(0)" ::: "memory"); \
    __builtin_amdgcn_s_barrier();                      \
  } while (0)

// ---------------------------------------------------------------------------
// Kernel 0: transpose + fp16-split W -> Wt_hi/Wt_lo [h][f] (scratch in d_out;
// flash_attn overwrites all of d_out afterwards).
// ---------------------------------------------------------------------------
__global__ __launch_bounds__(256) void wt_prep(
    const float* __restrict__ Wq, const float* __restrict__ Wk,
    const float* __restrict__ Wv, half_t* __restrict__ wth,
    half_t* __restrict__ wtl) {
  const int zi = blockIdx.z;
  const float* W = (zi == 0) ? Wq : (zi == 1) ? Wk : Wv;
  half_t* oh = wth + (size_t)zi * H_DIM * H_DIM;
  half_t* ol = wtl + (size_t)zi * H_DIM * H_DIM;
  const int h0 = blockIdx.x * 32, f0 = blockIdx.y * 32;
  __shared__ float Ws[32][33];
  const int t = threadIdx.x;
  const int c = t & 31, r8 = t >> 5;
#pragma unroll
  for (int rr = 0; rr < 4; rr++)
    Ws[r8 * 4 + rr][c] = W[(size_t)(f0 + r8 * 4 + rr) * H_DIM + h0 + c];
  __syncthreads();
#pragma unroll
  for (int rr = 0; rr < 4; rr++) {
    int h = r8 * 4 + rr;
    float v = Ws[c][h];
    half_t hi = (half_t)v;
    half_t lo = (half_t)(v - (float)hi);
    oh[(size_t)(h0 + h) * H_DIM + f0 + c] = hi;
    ol[(size_t)(h0 + h) * H_DIM + f0 + c] = lo;
  }
}

// ---------------------------------------------------------------------------
// Kernel 1: QKV projection on MFMA, 3-term fp16 split (hh + lh + hl).
// (unchanged)
// ---------------------------------------------------------------------------
#define QKV_BK 64

__global__ __launch_bounds__(256, 2) void qkv_mfma(
    const float* __restrict__ x, const half_t* __restrict__ wth,
    const half_t* __restrict__ wtl, const float* __restrict__ bq,
    const float* __restrict__ bk, const float* __restrict__ bv,
    half_t* __restrict__ ws) {
  const int zi = blockIdx.z;
  const half_t* Ah_g = wth + (size_t)zi * H_DIM * H_DIM;
  const half_t* Al_g = wtl + (size_t)zi * H_DIM * H_DIM;
  const float* bias = (zi == 0) ? bq : (zi == 1) ? bk : bv;
  half_t* out = ws + (size_t)zi * ((size_t)NB * S_LEN * H_DIM);
  const int m0 = blockIdx.x * 128;  // h
  const int n0 = blockIdx.y * 128;  // flattened b*s
  const int t = threadIdx.x;
  const int w = t >> 6, lane = t & 63, ln = lane & 15, quad = lane >> 4;

  __shared__ half_t Bs[16384];

  float4_t acc[2][8] = {};

  const int ss = t >> 1;
  const int fh = (t & 1) * 32;
  const int snt = ss >> 4, sln = ss & 15;

  for (int k0 = 0; k0 < H_DIM; k0 += QKV_BK) {
    half8_t ah[2][2], al[2][2];
#pragma unroll
    for (int i = 0; i < 2; i++) {
      const size_t arow =
          (size_t)(m0 + w * 32 + i * 16 + ln) * H_DIM + k0 + quad * 8;
#pragma unroll
      for (int k2 = 0; k2 < 2; k2++) {
        ah[i][k2] = *(const half8_t*)(Ah_g + arow + k2 * 32);
        al[i][k2] = *(const half8_t*)(Al_g + arow + k2 * 32);
      }
    }
    __syncthreads();
    {
      const float* xp = x + (size_t)(n0 + ss) * H_DIM + k0 + fh;
#pragma unroll
      for (int g = 0; g < 4; g++) {
        float4 v0 = *(const float4*)(xp + g * 8);
        float4 v1 = *(const float4*)(xp + g * 8 + 4);
        float vv[8] = {v0.x, v0.y, v0.z, v0.w, v1.x, v1.y, v1.z, v1.w};
        half8_t hhi, hlo;
#pragma unroll
        for (int j = 0; j < 8; j++) {
          half_t h = (half_t)vv[j];
          hhi[j] = h;
          hlo[j] = (half_t)(vv[j] - (float)h);
        }
        int f = fh + g * 8;
        int k2 = f >> 5, qd = (f >> 3) & 3;
        int base = ((k2 * 8 + snt) * 64 + qd * 16 + sln) * 8;
        *(half8_t*)&Bs[base] = hhi;
        *(half8_t*)&Bs[8192 + base] = hlo;
      }
    }
    __syncthreads();
#pragma unroll
    for (int k2 = 0; k2 < 2; k2++) {
#pragma unroll
      for (int nt = 0; nt < 8; nt++) {
        int base = ((k2 * 8 + nt) * 64 + lane) * 8;
        half8_t bh = *(const half8_t*)&Bs[base];
        half8_t bl = *(const half8_t*)&Bs[8192 + base];
        acc[0][nt] = MFMA16(ah[0][k2], bh, acc[0][nt]);
        acc[1][nt] = MFMA16(ah[1][k2], bh, acc[1][nt]);
        acc[0][nt] = MFMA16(al[0][k2], bh, acc[0][nt]);
        acc[1][nt] = MFMA16(al[1][k2], bh, acc[1][nt]);
        acc[0][nt] = MFMA16(ah[0][k2], bl, acc[0][nt]);
        acc[1][nt] = MFMA16(ah[1][k2], bl, acc[1][nt]);
      }
    }
  }

  const float oscale = (zi == 0) ? 0.03125f : 1.0f;
  float bb[2][4];
#pragma unroll
  for (int i = 0; i < 2; i++)
#pragma unroll
    for (int r = 0; r < 4; r++)
      bb[i][r] = bias[m0 + w * 32 + i * 16 + quad * 4 + r];

  if (zi < 2) {
#pragma unroll
    for (int i = 0; i < 2; i++)
#pragma unroll
      for (int nt = 0; nt < 8; nt++) {
        half4_t h4;
#pragma unroll
        for (int r = 0; r < 4; r++)
          h4[r] = (half_t)((acc[i][nt][r] + bb[i][r]) * oscale);
        size_t s = n0 + nt * 16 + ln;
        *(half4_t*)&out[s * H_DIM + m0 + w * 32 + i * 16 + quad * 4] = h4;
      }
  } else {
#pragma unroll
    for (int i = 0; i < 2; i++)
#pragma unroll
      for (int nt = 0; nt < 8; nt++) {
        int sf = n0 + nt * 16 + ln;
        int b = sf >> 12, si = sf & 4095;
#pragma unroll
        for (int r = 0; r < 4; r++) {
          int h = m0 + w * 32 + i * 16 + quad * 4 + r;
          out[((size_t)b * H_DIM + h) * S_LEN + si] =
              (half_t)(acc[i][nt][r] + bb[i][r]);
        }
      }
  }
}

// ---------------------------------------------------------------------------
// Kernel 2: MFMA flash attention, TQ=64 (512 threads, 8 waves, 1 block/CU).
// (a) LDS-only barriers (no vmcnt(0) drain -> K/V prefetch stays in flight
// across phase boundaries); (b) softmax running state (m, l) in per-lane
// registers, redundantly maintained by every wave (lane<->q-row), removing
// barrier W2 and both single-wave serial sections; (c) K ring for tile kt+TK
// issued right after phase A (covered by softmax+PV); (d) phase C kc-major
// (pa[4] + vr[4] ring) to cut live VGPRs.
// LDS: Qs 128 KB + Ps 16 KB + wmax/wl 4 KB.
// ---------------------------------------------------------------------------
#define TQ 64
#define TK 128

__global__ __launch_bounds__(512, 2) void flash_attn(
    const half_t* __restrict__ qw, const half_t* __restrict__ kw,
    const half_t* __restrict__ vt, float* __restrict__ out) {
  // batch -> 2 XCDs; 32 blocks/XCD share one K/V stream, 1 block/CU.
  const int slot = blockIdx.x & 7;
  const int b = slot >> 1;
  const int qb = ((blockIdx.x >> 3) << 1) | (slot & 1);
  const int q0 = qb * TQ;
  const int t = threadIdx.x;
  const int w = t >> 6;
  const int lane = t & 63;
  const int ln = lane & 15;
  const int quad = lane >> 4;

  __shared__ half_t Qs[65536];  // [rs(4)][ks(32)][lane(64)][8] = 128 KB
  __shared__ half_t Ps[8192];   // [rs(4)][kc(4)][lane(64)][8] = 16 KB
  __shared__ float wmax[8][64];
  __shared__ float wl[8][64];

  const half_t* qp = qw + ((size_t)b * S_LEN + q0) * H_DIM;
  const half_t* kbp = kw + (size_t)b * S_LEN * H_DIM;
  const half_t* vbt = vt + (size_t)b * H_DIM * S_LEN;

  // K ring prologue for kt=0 (issued before Q staging so it lands early)
  const half_t* kr = kbp + (size_t)(w * 16 + ln) * H_DIM + quad * 8;
  half8_t kbuf[6];
#pragma unroll
  for (int d = 0; d < 6; d++) kbuf[d] = *(const half8_t*)(kr + d * 32);

  // stage Q tile into fragment order
#pragma unroll
  for (int i = 0; i < 16; i++) {
    int flat = t * 8 + i * 4096;
    int r = flat >> 10, c = flat & 1023;
    int rs = r >> 4, lq = r & 15, ks = c >> 5, qd = (c >> 3) & 3;
    *(half8_t*)&Qs[((rs * 32 + ks) * 64 + qd * 16 + lq) * 8] =
        *(const half8_t*)&qp[(size_t)r * H_DIM + c];
  }
  BAR_LDS();

  // per-lane softmax running state, lane <-> q row (all waves redundant)
  float m_l = -1e30f;
  float l_l = 0.0f;

  float4_t O[4][8] = {};  // [rs(4 row-tiles)][j(8 col-tiles in h-chunk w)]

  for (int kt = 0; kt < S_LEN; kt += TK) {
    // ---------------- phase A: S = Q . K^T ----------------
    // wave w: K rows kt + w*16 .. +16 (S-cols of the 128 tile), all 4 Q
    // row-sets; K tile read once per block. kbuf preloaded by prev iter.
    float4_t s[4] = {};
    __builtin_amdgcn_s_setprio(1);
#pragma unroll
    for (int ks = 0; ks < 32; ks++) {
      half8_t a0 = *(const half8_t*)&Qs[(ks * 64 + lane) * 8];
      half8_t a1 = *(const half8_t*)&Qs[16384 + (ks * 64 + lane) * 8];
      half8_t a2 = *(const half8_t*)&Qs[32768 + (ks * 64 + lane) * 8];
      half8_t a3 = *(const half8_t*)&Qs[49152 + (ks * 64 + lane) * 8];
      half8_t kc = kbuf[ks % 6];
      if (ks < 26) kbuf[ks % 6] = *(const half8_t*)(kr + (ks + 6) * 32);
      s[0] = MFMA16(a0, kc, s[0]);
      s[1] = MFMA16(a1, kc, s[1]);
      s[2] = MFMA16(a2, kc, s[2]);
      s[3] = MFMA16(a3, kc, s[3]);
    }
    __builtin_amdgcn_s_setprio(0);

    // K prefetch for NEXT tile — in flight across softmax + phase C
    kr += (size_t)TK * H_DIM;
    if (kt + TK < S_LEN) {
#pragma unroll
      for (int d = 0; d < 6; d++) kbuf[d] = *(const half8_t*)(kr + d * 32);
    }

    // V ring prefetch (j=0..3 of kc=0) — in flight across softmax
    const half_t* vbase = vbt + (size_t)(w * 128 + ln) * S_LEN + kt + quad * 8;
    half8_t vr[4];
#pragma unroll
    for (int j = 0; j < 4; j++)
      vr[j] = *(const half8_t*)(vbase + (size_t)j * 16 * S_LEN);

    // ---------------- softmax stats ----------------
    // s[rs][r]: row q = rs*16 + quad*4 + r, col = w*16 + ln.
    float rm[4][4];
#pragma unroll
    for (int rs = 0; rs < 4; rs++)
#pragma unroll
      for (int r = 0; r < 4; r++) rm[rs][r] = s[rs][r];
#pragma unroll
    for (int off = 1; off < 16; off <<= 1)
#pragma unroll
      for (int rs = 0; rs < 4; rs++)
#pragma unroll
        for (int r = 0; r < 4; r++)
          rm[rs][r] = fmaxf(rm[rs][r], __shfl_xor(rm[rs][r], off));
    if (ln == 0)
#pragma unroll
      for (int rs = 0; rs < 4; rs++)
#pragma unroll
        for (int r = 0; r < 4; r++)
          wmax[w][rs * 16 + quad * 4 + r] = rm[rs][r];
    BAR_LDS();  // W1

    // every wave redundantly updates running max for q = lane
    float nm_l = m_l;
#pragma unroll
    for (int w2 = 0; w2 < 8; w2++) nm_l = fmaxf(nm_l, wmax[w2][lane]);
    float aS_l = __expf(m_l - nm_l);
    m_l = nm_l;

    // ---- P = exp(S - m) -> Ps (fragment order), O rescale fused ----
    const int pbase = (w >> 1) * 512 + (w & 1) * 256 + (ln >> 3) * 128 +
                      quad * 32 + (ln & 7);
    float pl[4][4];
#pragma unroll
    for (int rs = 0; rs < 4; rs++)
#pragma unroll
      for (int r = 0; r < 4; r++) {
        const int q = rs * 16 + quad * 4 + r;
        float nmq = __shfl(m_l, q);
        float aq = __shfl(aS_l, q);
        float p = __expf(s[rs][r] - nmq);
        pl[rs][r] = p;
        Ps[pbase + rs * 2048 + r * 8] = (half_t)p;
#pragma unroll
        for (int j = 0; j < 8; j++) O[rs][j][r] *= aq;
      }
#pragma unroll
    for (int off = 1; off < 16; off <<= 1)
#pragma unroll
      for (int rs = 0; rs < 4; rs++)
#pragma unroll
        for (int r = 0; r < 4; r++) pl[rs][r] += __shfl_xor(pl[rs][r], off);
    if (ln == 0)
#pragma unroll
      for (int rs = 0; rs < 4; rs++)
#pragma unroll
        for (int r = 0; r < 4; r++)
          wl[w][rs * 16 + quad * 4 + r] = pl[rs][r];
    BAR_LDS();  // W3

    // every wave redundantly updates running denom for q = lane
    float s8_l = 0.f;
#pragma unroll
    for (int w2 = 0; w2 < 8; w2++) s8_l += wl[w2][lane];
    l_l = l_l * aS_l + s8_l;

    // ---------------- phase C: O += P @ V (kc-major) ----------------
#pragma unroll
    for (int kc = 0; kc < 4; kc++) {
      half8_t pa[4];
#pragma unroll
      for (int rs = 0; rs < 4; rs++)
        pa[rs] = *(const half8_t*)&Ps[((rs * 4 + kc) * 64 + lane) * 8];
      __builtin_amdgcn_s_setprio(1);
#pragma unroll
      for (int j = 0; j < 8; j++) {
        half8_t vc = vr[j & 3];
        const int jn = j + 4;
        if (jn < 8) {
          vr[j & 3] =
              *(const half8_t*)(vbase + (size_t)jn * 16 * S_LEN + kc * 32);
        } else if (kc < 3) {
          vr[j & 3] = *(const half8_t*)(vbase + (size_t)(jn - 8) * 16 * S_LEN +
                                        (kc + 1) * 32);
        }
#pragma unroll
        for (int rs = 0; rs < 4; rs++)
          O[rs][j] = MFMA16(pa[rs], vc, O[rs][j]);
      }
      __builtin_amdgcn_s_setprio(0);
    }
  }

  // ---------------- epilogue ----------------
  float il[4][4];
#pragma unroll
  for (int rs = 0; rs < 4; rs++)
#pragma unroll
    for (int r = 0; r < 4; r++)
      il[rs][r] = 1.0f / __shfl(l_l, rs * 16 + quad * 4 + r);
  float* ob = out + ((size_t)b * S_LEN + q0) * H_DIM + w * 128 + ln;
#pragma unroll
  for (int rs = 0; rs < 4; rs++)
#pragma unroll
    for (int j = 0; j < 8; j++)
#pragma unroll
      for (int r = 0; r < 4; r++)
        ob[(size_t)(rs * 16 + quad * 4 + r) * H_DIM + j * 16] =
            O[rs][j][r] * il[rs][r];
}

// ---------------------------------------------------------------------------
extern "C" void kernel_launch(void* const* d_in, const int* in_sizes, int n_in,
                              void* d_out, int out_size, void* d_ws,
                              size_t ws_size, hipStream_t stream) {
  const float* x = (const float*)d_in[0];
  const float* Wq = (const float*)d_in[1];
  const float* bq = (const float*)d_in[2];
  const float* Wk = (const float*)d_in[3];
  const float* bk = (const float*)d_in[4];
  const float* Wv = (const float*)d_in[5];
  const float* bv = (const float*)d_in[6];
  half_t* ws = (half_t*)d_ws;  // q(32MB) | k(32MB) | vt(32MB, transposed)
  float* out = (float*)d_out;

  half_t* wth = (half_t*)d_out;  // scratch; overwritten by flash_attn
  half_t* wtl = wth + (size_t)3 * H_DIM * H_DIM;

  wt_prep<<<dim3(32, 32, 3), 256, 0, stream>>>(Wq, Wk, Wv, wth, wtl);

  qkv_mfma<<<dim3(8, 128, 3), 256, 0, stream>>>(x, wth, wtl, bq, bk, bv, ws);

  const half_t* qw = ws;
  const half_t* kw = ws + (size_t)NB * S_LEN * H_DIM;
  const half_t* vt = ws + 2 * (size_t)NB * S_LEN * H_DIM;
  flash_attn<<<dim3((S_LEN / TQ) * NB), 512, 0, stream>>>(qw, kw, vt, out);
}